// Round 13
// baseline (238.197 us; speedup 1.0000x reference)
//
#include <hip/hip_runtime.h>
#include <math.h>

#define BATCH 64
#define HH 512
#define WW 512
#define KRAD 15
#define KSZ 31
#define NTOT ((size_t)BATCH * HH * WW)
#define TILE_Y 64
#define NCHUNK (HH / TILE_Y)            // 8
#define NBLK (BATCH * NCHUNK)           // 512 blocks
#define RING 64                         // fp16 ring rows (64 KB, &63 free)

typedef _Float16 h8 __attribute__((ext_vector_type(8)));

// Wave64 inclusive add-scan via DPP (LLVM AMDGPUAtomicOptimizer sequence).
__device__ __forceinline__ float dpp_scan_add(float v) {
    int t;
    t = __builtin_amdgcn_update_dpp(0, __float_as_int(v), 0x111, 0xf, 0xf, false); // row_shr:1
    v += __int_as_float(t);
    t = __builtin_amdgcn_update_dpp(0, __float_as_int(v), 0x112, 0xf, 0xf, false); // row_shr:2
    v += __int_as_float(t);
    t = __builtin_amdgcn_update_dpp(0, __float_as_int(v), 0x114, 0xf, 0xf, false); // row_shr:4
    v += __int_as_float(t);
    t = __builtin_amdgcn_update_dpp(0, __float_as_int(v), 0x118, 0xf, 0xf, false); // row_shr:8
    v += __int_as_float(t);
    t = __builtin_amdgcn_update_dpp(0, __float_as_int(v), 0x142, 0xa, 0xf, false); // row_bcast:15 -> rows 1,3
    v += __int_as_float(t);
    t = __builtin_amdgcn_update_dpp(0, __float_as_int(v), 0x143, 0xc, 0xf, false); // row_bcast:31 -> rows 2,3
    v += __int_as_float(t);
    return v;
}

// ---------------------------------------------------------------------------
// ROUND 13 = R6 (best verified: 42-51us, VGPR 32, absmax 0.0 x3) + explicit
// software-pipelined t/L global loads in the compute loop.
// Evidence: R6/R10/R12 all 42-55us with nothing saturated and VGPR=32 ->
// compiler issues t/L loads immediately before use (min-reg policy under the
// (1024,8) cap); all 32 waves/CU stall on VMEM latency in lockstep. Fix:
// double-buffered batch-of-4 prefetch in named registers (+16 VGPR, static
// indices only), loads issue one batch (~400+ cyc of VALU) ahead of use.
// Scan phases byte-identical to R6 (validated 3x).
//   scan rel 0..61 -> B -> compute rows 0..31 -> B -> scan rel 62..93
//   (slots 62,63,0..29; live 30..61 untouched) -> B -> compute rows 32..63.
// ---------------------------------------------------------------------------
__global__ __launch_bounds__(1024, 8) void mega_kernel(const float* __restrict__ logits,
                                                       const float* __restrict__ targ,
                                                       float* __restrict__ pbuf) {
    __shared__ _Float16 Hring[RING * WW];   // 64 KB
    __shared__ float red[3][16];

    const int b     = blockIdx.x >> 3;          // batch
    const int chunk = blockIdx.x & (NCHUNK - 1);
    const int y0    = chunk * TILE_Y;

    const int wave = threadIdx.x >> 6;          // 0..15
    const int lane = threadIdx.x & 63;

    // Scan one row (rel = y_abs-(y0-15)): prefix -> round-trip -> windowed H.
    auto scan_row = [&](int rel) {
        const int slot = rel & (RING - 1);
        _Float16* row = &Hring[slot * WW];
        const int y_abs = y0 - KRAD + rel;

        if (y_abs < 0 || y_abs >= HH) {          // zero-pad rows (wave-uniform)
            *(h8*)&row[lane * 8] = (h8){};
            return;
        }

        const float4* rp = (const float4*)(targ + ((size_t)b * HH + y_abs) * WW);
        float4 a  = rp[2 * lane];
        float4 b4 = rp[2 * lane + 1];
        float v[8] = {a.x, a.y, a.z, a.w, b4.x, b4.y, b4.z, b4.w};

        float T = 0.0f;
        float P[8];
#pragma unroll
        for (int j = 0; j < 8; ++j) { T += v[j]; P[j] = T; }

        const float incl = dpp_scan_add(T);
        const float excl = incl - T;
        h8 hv;
#pragma unroll
        for (int j = 0; j < 8; ++j) hv[j] = (_Float16)(P[j] + excl);
        *(h8*)&row[lane * 8] = hv;               // publish P

        const float Ptot = __shfl(incl, 63);     // P[511] (row total)

        // ensure P store retired before shifted reads (and pin order)
        asm volatile("s_waitcnt lgkmcnt(0)" ::: "memory");

        // shifted aligned reads of our own row
        h8 lo8 = (h8){};
        if (lane >= 2) lo8 = *(const h8*)&row[lane * 8 - 16];   // P[x-16..x-9]
        const int eA = (lane * 8 + 8  <= WW - 8) ? (lane * 8 + 8)  : (WW - 8);
        const int eB = (lane * 8 + 16 <= WW - 8) ? (lane * 8 + 16) : (WW - 8);
        const h8 A8 = *(const h8*)&row[eA];      // P[xe+8 .. xe+15]
        const h8 B8 = *(const h8*)&row[eB];      // P[xe+16 .. xe+23]

        const int xe = lane * 8;
        float Hv[8];
        {
            const float hi0 = (xe > 496) ? Ptot : (float)A8[7];   // P[xe+15]
            Hv[0] = hi0 - (float)lo8[0];
#pragma unroll
            for (int j = 1; j < 8; ++j) {
                const float hij = (xe + j > 496) ? Ptot : (float)B8[j - 1]; // P[xe+j+15]
                Hv[j] = hij - (float)lo8[j];
            }
        }
        h8 hw;
#pragma unroll
        for (int j = 0; j < 8; ++j) hw[j] = (_Float16)Hv[j];
        *(h8*)&row[lane * 8] = hw;               // overwrite slot with H
    };

    // ---- Phase A scan: rel 0..61 (slots 0..61) ----
#pragma unroll
    for (int i = 0; i < 4; ++i) {
        const int rel = wave + 16 * i;
        if (rel < 62) scan_row(rel);
    }
    __syncthreads();

    // ---- Compute setup: ALL threads. Column x, vertical half. ----
    const int x    = threadIdx.x & (WW - 1);    // 0..511
    const int half = threadIdx.x >> 9;          // 0 or 1
    const _Float16* colH = &Hring[x];
    const float* Tp = targ   + ((size_t)b * HH + y0) * WW + x;
    const float* Lp = logits + ((size_t)b * HH + y0) * WW + x;
    const float inv_ksq = 1.0f / (float)(KSZ * KSZ);
    float a_wbce = 0.0f, a_int = 0.0f, a_tot = 0.0f;

    // H(rel, x): ONE conflict-free ds_read_u16
    auto Hval = [&](int rel) -> float {
        return (float)colH[(rel & (RING - 1)) * WW];
    };

    // One 16-row strip starting at absolute row ys. Rolling vsum + inline
    // loss; t/L loads software-pipelined one batch-of-4 ahead (all indices
    // static after unroll -> registers, no scratch).
    auto do16 = [&](int ys) {
        float s0 = 0.0f, s1 = 0.0f, s2 = 0.0f, s3 = 0.0f;
#pragma unroll
        for (int r = 0; r < 28; r += 4) {
            s0 += Hval(ys + r);
            s1 += Hval(ys + r + 1);
            s2 += Hval(ys + r + 2);
            s3 += Hval(ys + r + 3);
        }
        s0 += Hval(ys + 28);
        s1 += Hval(ys + 29);
        s2 += Hval(ys + 30);
        float vsum = (s0 + s1) + (s2 + s3);

        // prefetch batch 0 (rows ys..ys+3)
        float tj0, tj1, tj2, tj3, Lj0, Lj1, Lj2, Lj3;
        tj0 = Tp[(size_t)(ys + 0) * WW];
        tj1 = Tp[(size_t)(ys + 1) * WW];
        tj2 = Tp[(size_t)(ys + 2) * WW];
        tj3 = Tp[(size_t)(ys + 3) * WW];
        Lj0 = __builtin_nontemporal_load(Lp + (size_t)(ys + 0) * WW);
        Lj1 = __builtin_nontemporal_load(Lp + (size_t)(ys + 1) * WW);
        Lj2 = __builtin_nontemporal_load(Lp + (size_t)(ys + 2) * WW);
        Lj3 = __builtin_nontemporal_load(Lp + (size_t)(ys + 3) * WW);

#pragma unroll
        for (int jb = 0; jb < 4; ++jb) {
            // issue next batch's loads BEFORE consuming this batch
            float tn0 = 0.f, tn1 = 0.f, tn2 = 0.f, tn3 = 0.f;
            float Ln0 = 0.f, Ln1 = 0.f, Ln2 = 0.f, Ln3 = 0.f;
            if (jb < 3) {
                const int yn = ys + 4 * (jb + 1);
                tn0 = Tp[(size_t)(yn + 0) * WW];
                tn1 = Tp[(size_t)(yn + 1) * WW];
                tn2 = Tp[(size_t)(yn + 2) * WW];
                tn3 = Tp[(size_t)(yn + 3) * WW];
                Ln0 = __builtin_nontemporal_load(Lp + (size_t)(yn + 0) * WW);
                Ln1 = __builtin_nontemporal_load(Lp + (size_t)(yn + 1) * WW);
                Ln2 = __builtin_nontemporal_load(Lp + (size_t)(yn + 2) * WW);
                Ln3 = __builtin_nontemporal_load(Lp + (size_t)(yn + 3) * WW);
            }
#pragma unroll
            for (int k = 0; k < 4; ++k) {
                const int j = 4 * jb + k;
                if (j > 0)
                    vsum += Hval(ys + j + 30) - Hval(ys + j - 1);

                const float t = (k == 0) ? tj0 : (k == 1) ? tj1 : (k == 2) ? tj2 : tj3;
                const float L = (k == 0) ? Lj0 : (k == 1) ? Lj1 : (k == 2) ? Lj2 : Lj3;

                const float s = vsum * inv_ksq;
                const float weit = 1.0f + 5.0f * fabsf(s - t);
                const float e  = __expf(-fabsf(L));
                const float r  = __builtin_amdgcn_rcpf(1.0f + e);
                const float lg = __logf(1.0f + e);          // softplus(-|L|)
                const float sp  = fmaxf(L, 0.0f) + lg;      // softplus(L)
                const float bce = sp - t * L;
                const float p   = (L >= 0.0f) ? r : e * r;  // sigmoid(L)

                a_wbce += weit * bce;
                a_int  += p * t * weit;
                a_tot  += (p + t) * weit;
            }
            tj0 = tn0; tj1 = tn1; tj2 = tn2; tj3 = tn3;
            Lj0 = Ln0; Lj1 = Ln1; Lj2 = Ln2; Lj3 = Ln3;
        }
    };

    // ---- Phase A compute: rows 0..31 across both halves (slots 0..61) ----
    do16(half * 16);
    __syncthreads();

    // ---- Phase B scan: rel 62..93 -> slots 62,63,0..29 (live 30..61 kept) ----
    scan_row(62 + wave);
    scan_row(78 + wave);
    __syncthreads();

    // ---- Phase B compute: rows 32..63 across both halves ----
    do16(32 + half * 16);

    // ---- Block reduction ----
#pragma unroll
    for (int off = 32; off > 0; off >>= 1) {
        a_wbce += __shfl_down(a_wbce, off, 64);
        a_int  += __shfl_down(a_int,  off, 64);
        a_tot  += __shfl_down(a_tot,  off, 64);
    }

    if (lane == 0) {
        red[0][wave] = a_wbce; red[1][wave] = a_int; red[2][wave] = a_tot;
    }
    __syncthreads();
    if (threadIdx.x == 0) {
        float w = 0.0f, i2 = 0.0f, t2 = 0.0f;
#pragma unroll
        for (int k = 0; k < 16; ++k) { w += red[0][k]; i2 += red[1][k]; t2 += red[2][k]; }
        pbuf[blockIdx.x]            = w;
        pbuf[NBLK + blockIdx.x]     = i2;
        pbuf[2 * NBLK + blockIdx.x] = t2;
    }
}

// ---------------------------------------------------------------------------
// Finalize: reduce 512 partials per quantity (double accum) + scalar.
// ---------------------------------------------------------------------------
__global__ __launch_bounds__(256) void finalize_kernel(const float* __restrict__ pbuf,
                                                       float* __restrict__ out) {
    const int tidx = threadIdx.x;
    double w = 0.0, i2 = 0.0, t2 = 0.0;
    for (int k = tidx; k < NBLK; k += 256) {
        w  += (double)pbuf[k];
        i2 += (double)pbuf[NBLK + k];
        t2 += (double)pbuf[2 * NBLK + k];
    }
#pragma unroll
    for (int off = 32; off > 0; off >>= 1) {
        w  += __shfl_down(w,  off, 64);
        i2 += __shfl_down(i2, off, 64);
        t2 += __shfl_down(t2, off, 64);
    }
    __shared__ double red[3][4];
    const int wave = tidx >> 6;
    if ((tidx & 63) == 0) { red[0][wave] = w; red[1][wave] = i2; red[2][wave] = t2; }
    __syncthreads();
    if (tidx == 0) {
        double ws = 0.0, is = 0.0, ts = 0.0;
        for (int k = 0; k < 4; ++k) { ws += red[0][k]; is += red[1][k]; ts += red[2][k]; }
        const double wbce   = ws / (double)NTOT;
        const double union_ = ts - is;
        const double wiou   = 1.0 - (is + 1.0) / (union_ + 1.0);
        out[0] = (float)(wbce + wiou);
    }
}

extern "C" void kernel_launch(void* const* d_in, const int* in_sizes, int n_in,
                              void* d_out, int out_size, void* d_ws, size_t ws_size,
                              hipStream_t stream) {
    const float* logits = (const float*)d_in[0];
    const float* targ   = (const float*)d_in[1];
    float* out          = (float*)d_out;
    float* pbuf         = (float*)d_ws;     // 3*NBLK floats (6 KB)

    mega_kernel<<<NBLK, 1024, 0, stream>>>(logits, targ, pbuf);
    finalize_kernel<<<1, 256, 0, stream>>>(pbuf, out);
}

// Round 15
// 155.804 us; speedup vs baseline: 1.5288x; 1.5288x over previous
//
#include <hip/hip_runtime.h>
#include <math.h>

#define BATCH 64
#define HH 512
#define WW 512
#define KRAD 15
#define KSZ 31
#define NTOT ((size_t)BATCH * HH * WW)
#define TILE_Y 64
#define NCHUNK (HH / TILE_Y)            // 8
#define NBLK (BATCH * NCHUNK)           // 512 blocks
#define RING 64                         // fp16 ring rows (64 KB, &63 free)
#define NWAVE 8                         // 512-thread block

typedef _Float16 h8 __attribute__((ext_vector_type(8)));

// Wave64 inclusive add-scan via DPP (LLVM AMDGPUAtomicOptimizer sequence).
__device__ __forceinline__ float dpp_scan_add(float v) {
    int t;
    t = __builtin_amdgcn_update_dpp(0, __float_as_int(v), 0x111, 0xf, 0xf, false); // row_shr:1
    v += __int_as_float(t);
    t = __builtin_amdgcn_update_dpp(0, __float_as_int(v), 0x112, 0xf, 0xf, false); // row_shr:2
    v += __int_as_float(t);
    t = __builtin_amdgcn_update_dpp(0, __float_as_int(v), 0x114, 0xf, 0xf, false); // row_shr:4
    v += __int_as_float(t);
    t = __builtin_amdgcn_update_dpp(0, __float_as_int(v), 0x118, 0xf, 0xf, false); // row_shr:8
    v += __int_as_float(t);
    t = __builtin_amdgcn_update_dpp(0, __float_as_int(v), 0x142, 0xa, 0xf, false); // row_bcast:15 -> rows 1,3
    v += __int_as_float(t);
    t = __builtin_amdgcn_update_dpp(0, __float_as_int(v), 0x143, 0xc, 0xf, false); // row_bcast:31 -> rows 2,3
    v += __int_as_float(t);
    return v;
}

// ---------------------------------------------------------------------------
// ROUND 15 (= R14 resubmitted; broker timeout) — R6's validated algorithm at
// __launch_bounds__(512,4).
// Evidence: (1024,8) pins the allocator at 32 VGPRs and spills ANY extra
// state (R7/R9/R11/R13: 168-245 MB scratch). (512,4) held 52 regs spill-free
// (R10). This kernel = R6's work-shape (TILE_Y=64, 64KB H-ring, 2-phase,
// scalar per-column compute) + register slack + depth-1 t/L prefetch.
//   8 waves: scan 94 rows (8+4 rows/wave). Compute: 1 thread/column,
//   32 rows/phase.
//   scan rel 0..61 -> B -> compute rows 0..31 -> B -> scan rel 62..93
//   (slots 62,63,0..29; live 30..61 untouched) -> B -> compute rows 32..63.
// LDS 64KB -> still 2 blocks/CU (128KB < 160KB): cross-block phase overlap.
// ---------------------------------------------------------------------------
__global__ __launch_bounds__(512, 4) void mega_kernel(const float* __restrict__ logits,
                                                      const float* __restrict__ targ,
                                                      float* __restrict__ pbuf) {
    __shared__ _Float16 Hring[RING * WW];   // 64 KB
    __shared__ float red[3][NWAVE];

    const int b     = blockIdx.x >> 3;          // batch
    const int chunk = blockIdx.x & (NCHUNK - 1);
    const int y0    = chunk * TILE_Y;

    const int wave = threadIdx.x >> 6;          // 0..7
    const int lane = threadIdx.x & 63;

    // Scan one row (rel = y_abs-(y0-15)): prefix -> round-trip -> windowed H.
    // (Byte-identical math to R6: validated absmax 0.0 four times.)
    auto scan_row = [&](int rel) {
        const int slot = rel & (RING - 1);
        _Float16* row = &Hring[slot * WW];
        const int y_abs = y0 - KRAD + rel;

        if (y_abs < 0 || y_abs >= HH) {          // zero-pad rows (wave-uniform)
            *(h8*)&row[lane * 8] = (h8){};
            return;
        }

        const float4* rp = (const float4*)(targ + ((size_t)b * HH + y_abs) * WW);
        float4 a  = rp[2 * lane];
        float4 b4 = rp[2 * lane + 1];
        float v[8] = {a.x, a.y, a.z, a.w, b4.x, b4.y, b4.z, b4.w};

        float T = 0.0f;
        float P[8];
#pragma unroll
        for (int j = 0; j < 8; ++j) { T += v[j]; P[j] = T; }

        const float incl = dpp_scan_add(T);
        const float excl = incl - T;
        h8 hv;
#pragma unroll
        for (int j = 0; j < 8; ++j) hv[j] = (_Float16)(P[j] + excl);
        *(h8*)&row[lane * 8] = hv;               // publish P

        const float Ptot = __shfl(incl, 63);     // P[511] (row total)

        // ensure P store retired before shifted reads (and pin order)
        asm volatile("s_waitcnt lgkmcnt(0)" ::: "memory");

        // shifted aligned reads of our own row
        h8 lo8 = (h8){};
        if (lane >= 2) lo8 = *(const h8*)&row[lane * 8 - 16];   // P[x-16..x-9]
        const int eA = (lane * 8 + 8  <= WW - 8) ? (lane * 8 + 8)  : (WW - 8);
        const int eB = (lane * 8 + 16 <= WW - 8) ? (lane * 8 + 16) : (WW - 8);
        const h8 A8 = *(const h8*)&row[eA];      // P[xe+8 .. xe+15]
        const h8 B8 = *(const h8*)&row[eB];      // P[xe+16 .. xe+23]

        const int xe = lane * 8;
        float Hv[8];
        {
            const float hi0 = (xe > 496) ? Ptot : (float)A8[7];   // P[xe+15]
            Hv[0] = hi0 - (float)lo8[0];
#pragma unroll
            for (int j = 1; j < 8; ++j) {
                const float hij = (xe + j > 496) ? Ptot : (float)B8[j - 1]; // P[xe+j+15]
                Hv[j] = hij - (float)lo8[j];
            }
        }
        h8 hw;
#pragma unroll
        for (int j = 0; j < 8; ++j) hw[j] = (_Float16)Hv[j];
        *(h8*)&row[lane * 8] = hw;               // overwrite slot with H
    };

    // ---- Phase A scan: rel 0..61 (slots 0..61), 8 waves x 8 rows ----
#pragma unroll
    for (int i = 0; i < 8; ++i) {
        const int rel = wave + 8 * i;
        if (rel < 62) scan_row(rel);
    }
    __syncthreads();

    // ---- Compute setup: one thread per column ----
    const int x = threadIdx.x;                  // 0..511
    const _Float16* colH = &Hring[x];
    const float* Tp = targ   + ((size_t)b * HH + y0) * WW + x;
    const float* Lp = logits + ((size_t)b * HH + y0) * WW + x;
    const float inv_ksq = 1.0f / (float)(KSZ * KSZ);
    float a_wbce = 0.0f, a_int = 0.0f, a_tot = 0.0f;

    // H(rel, x): ONE conflict-free ds_read_u16
    auto Hval = [&](int rel) -> float {
        return (float)colH[(rel & (RING - 1)) * WW];
    };

    // One 32-row strip starting at tile-row ys. Rolling vsum + inline loss;
    // depth-1 t/L prefetch (4 regs; affordable under the 128-reg cap).
    auto do32 = [&](int ys) {
        float s0 = 0.0f, s1 = 0.0f, s2 = 0.0f, s3 = 0.0f;
#pragma unroll
        for (int r = 0; r < 28; r += 4) {
            s0 += Hval(ys + r);
            s1 += Hval(ys + r + 1);
            s2 += Hval(ys + r + 2);
            s3 += Hval(ys + r + 3);
        }
        s0 += Hval(ys + 28);
        s1 += Hval(ys + 29);
        s2 += Hval(ys + 30);
        float vsum = (s0 + s1) + (s2 + s3);

        float tc = Tp[(size_t)ys * WW];
        float Lc = Lp[(size_t)ys * WW];

#pragma unroll 4
        for (int j = 0; j < 32; ++j) {
            // issue next row's t/L before consuming the current pair
            float tn = 0.0f, Ln = 0.0f;
            if (j < 31) {
                tn = Tp[(size_t)(ys + j + 1) * WW];
                Ln = Lp[(size_t)(ys + j + 1) * WW];
            }
            if (j > 0)
                vsum += Hval(ys + j + 30) - Hval(ys + j - 1);

            const float s = vsum * inv_ksq;
            const float t = tc;
            const float L = Lc;

            const float weit = 1.0f + 5.0f * fabsf(s - t);
            const float e  = __expf(-fabsf(L));
            const float r  = __builtin_amdgcn_rcpf(1.0f + e);
            const float lg = __logf(1.0f + e);          // softplus(-|L|)
            const float sp  = fmaxf(L, 0.0f) + lg;      // softplus(L)
            const float bce = sp - t * L;
            const float p   = (L >= 0.0f) ? r : e * r;  // sigmoid(L)

            a_wbce += weit * bce;
            a_int  += p * t * weit;
            a_tot  += (p + t) * weit;

            tc = tn; Lc = Ln;
        }
    };

    // ---- Phase A compute: rows 0..31 (window rel 0..61) ----
    do32(0);
    __syncthreads();

    // ---- Phase B scan: rel 62..93 -> slots 62,63,0..29 (live 30..61 kept) ----
    scan_row(62 + wave);
    scan_row(70 + wave);
    scan_row(78 + wave);
    scan_row(86 + wave);
    __syncthreads();

    // ---- Phase B compute: rows 32..63 (window rel 32..93) ----
    do32(32);

    // ---- Block reduction ----
#pragma unroll
    for (int off = 32; off > 0; off >>= 1) {
        a_wbce += __shfl_down(a_wbce, off, 64);
        a_int  += __shfl_down(a_int,  off, 64);
        a_tot  += __shfl_down(a_tot,  off, 64);
    }

    if (lane == 0) {
        red[0][wave] = a_wbce; red[1][wave] = a_int; red[2][wave] = a_tot;
    }
    __syncthreads();
    if (threadIdx.x == 0) {
        float w = 0.0f, i2 = 0.0f, t2 = 0.0f;
#pragma unroll
        for (int k = 0; k < NWAVE; ++k) { w += red[0][k]; i2 += red[1][k]; t2 += red[2][k]; }
        pbuf[blockIdx.x]            = w;
        pbuf[NBLK + blockIdx.x]     = i2;
        pbuf[2 * NBLK + blockIdx.x] = t2;
    }
}

// ---------------------------------------------------------------------------
// Finalize: reduce 512 partials per quantity (double accum) + scalar.
// ---------------------------------------------------------------------------
__global__ __launch_bounds__(256) void finalize_kernel(const float* __restrict__ pbuf,
                                                       float* __restrict__ out) {
    const int tidx = threadIdx.x;
    double w = 0.0, i2 = 0.0, t2 = 0.0;
    for (int k = tidx; k < NBLK; k += 256) {
        w  += (double)pbuf[k];
        i2 += (double)pbuf[NBLK + k];
        t2 += (double)pbuf[2 * NBLK + k];
    }
#pragma unroll
    for (int off = 32; off > 0; off >>= 1) {
        w  += __shfl_down(w,  off, 64);
        i2 += __shfl_down(i2, off, 64);
        t2 += __shfl_down(t2, off, 64);
    }
    __shared__ double red[3][4];
    const int wave = tidx >> 6;
    if ((tidx & 63) == 0) { red[0][wave] = w; red[1][wave] = i2; red[2][wave] = t2; }
    __syncthreads();
    if (tidx == 0) {
        double ws = 0.0, is = 0.0, ts = 0.0;
        for (int k = 0; k < 4; ++k) { ws += red[0][k]; is += red[1][k]; ts += red[2][k]; }
        const double wbce   = ws / (double)NTOT;
        const double union_ = ts - is;
        const double wiou   = 1.0 - (is + 1.0) / (union_ + 1.0);
        out[0] = (float)(wbce + wiou);
    }
}

extern "C" void kernel_launch(void* const* d_in, const int* in_sizes, int n_in,
                              void* d_out, int out_size, void* d_ws, size_t ws_size,
                              hipStream_t stream) {
    const float* logits = (const float*)d_in[0];
    const float* targ   = (const float*)d_in[1];
    float* out          = (float*)d_out;
    float* pbuf         = (float*)d_ws;     // 3*NBLK floats (6 KB)

    mega_kernel<<<NBLK, 512, 0, stream>>>(logits, targ, pbuf);
    finalize_kernel<<<1, 256, 0, stream>>>(pbuf, out);
}